// Round 1
// baseline (2405.707 us; speedup 1.0000x reference)
//
#include <hip/hip_runtime.h>
#include <hip/hip_bf16.h>

// out[b,n,f] = sum_{l,m} cg[l,m,n] * x1[b,l,f] * x2[b,m,f]
// B=20000, P=1, L=16, LOUT=49 (padded 64), F=512
// Strategy: per-b GEMM  OUT[64,512] = CG^T[64,256] (bf16, const) * O[256,512]
// where O[l*16+m, f] = x1[l,f]*x2[m,f], built on the fly in registers.

#define TP_L    16
#define TP_K    256   // 16*16
#define TP_NOUT 49
#define TP_NPAD 64
#define TP_F    512

typedef short short8 __attribute__((ext_vector_type(8)));
typedef float f32x4  __attribute__((ext_vector_type(4)));

static __device__ __forceinline__ short f2bf(float f) {
    // round-to-nearest-even fp32 -> bf16 (inputs are finite normals)
    unsigned u = __float_as_uint(f);
    u += 0x7fffu + ((u >> 16) & 1u);
    return (short)(u >> 16);
}

// Build padded transposed bf16 CG: cgT[n][k] = cg[l][m][n], k = l*16+m, n in [0,64)
// cg is [16][16][49] row-major => flat index k*49 + n.
__global__ void prep_cg_kernel(const float* __restrict__ cg, short* __restrict__ cgT) {
    int idx = blockIdx.x * 256 + threadIdx.x;   // 0 .. 64*256-1
    int n = idx >> 8;
    int k = idx & 255;
    float v = (n < TP_NOUT) ? cg[k * TP_NOUT + n] : 0.0f;
    cgT[idx] = f2bf(v);
}

__global__ void __launch_bounds__(512, 4) tp_kernel(
    const float* __restrict__ x1, const float* __restrict__ x2,
    const short* __restrict__ cgT, float* __restrict__ out)
{
    __shared__ float4 s1v[TP_L * TP_F / 4];   // 32 KB
    __shared__ float4 s2v[TP_L * TP_F / 4];   // 32 KB

    const int b   = blockIdx.x;
    const int tid = threadIdx.x;

    // ---- stage x1[b], x2[b] (16x512 fp32 each) into LDS, float4-coalesced ----
    const float4* g1 = (const float4*)(x1 + (size_t)b * (TP_L * TP_F));
    const float4* g2 = (const float4*)(x2 + (size_t)b * (TP_L * TP_F));
#pragma unroll
    for (int i = 0; i < 4; ++i) {
        s1v[tid + i * 512] = g1[tid + i * 512];
        s2v[tid + i * 512] = g2[tid + i * 512];
    }
    __syncthreads();

    const float* sx1 = (const float*)s1v;
    const float* sx2 = (const float*)s2v;

    const int lane = tid & 63;
    const int w    = tid >> 6;      // wave 0..7 -> f range [w*64, w*64+64)
    const int fl   = lane & 15;     // f within 16-tile; also A-row within n-tile
    const int g    = lane >> 4;     // quarter-wave 0..3
    const int hg   = g >> 1;        // 0..1 : which l within the k-step pair
    const int qg   = g & 1;         // 0..1 : which m-octet
    const int fb   = w * 64;

    f32x4 acc[4][4];                // [n-tile][f-tile]
#pragma unroll
    for (int nt = 0; nt < 4; ++nt)
#pragma unroll
        for (int ft = 0; ft < 4; ++ft)
            acc[nt][ft] = (f32x4){0.f, 0.f, 0.f, 0.f};

    // K loop: 8 steps of K=32.  k = 32s + 8g + i  ->  l = 2s+hg, m = 8*qg+i
#pragma unroll
    for (int s = 0; s < 8; ++s) {
        short8 a[4];
#pragma unroll
        for (int nt = 0; nt < 4; ++nt) {
            // A[r=fl][kk=8g+i] = cgT[nt*16+fl][32s + 8g + i], 16B contiguous
            a[nt] = *(const short8*)(cgT + (nt * 16 + fl) * TP_K + s * 32 + g * 8);
        }
#pragma unroll
        for (int ft = 0; ft < 4; ++ft) {
            const int f = fb + ft * 16 + fl;
            const float x1v = sx1[(2 * s + hg) * TP_F + f];
            const float* x2c = &sx2[(qg * 8) * TP_F + f];
            short8 bfr;
#pragma unroll
            for (int i = 0; i < 8; ++i) {
                bfr[i] = f2bf(x1v * x2c[i * TP_F]);
            }
#pragma unroll
            for (int nt = 0; nt < 4; ++nt) {
                acc[nt][ft] = __builtin_amdgcn_mfma_f32_16x16x32_bf16(
                    a[nt], bfr, acc[nt][ft], 0, 0, 0);
            }
        }
    }

    // ---- epilogue: D row = 4g + j (n within tile), col = fl (f within tile) ----
    float* outb = out + (size_t)b * (TP_NOUT * TP_F);
#pragma unroll
    for (int nt = 0; nt < 4; ++nt) {
#pragma unroll
        for (int j = 0; j < 4; ++j) {
            const int n = nt * 16 + g * 4 + j;
            if (n < TP_NOUT) {
#pragma unroll
                for (int ft = 0; ft < 4; ++ft) {
                    outb[n * TP_F + fb + ft * 16 + fl] = acc[nt][ft][j];
                }
            }
        }
    }
}

extern "C" void kernel_launch(void* const* d_in, const int* in_sizes, int n_in,
                              void* d_out, int out_size, void* d_ws, size_t ws_size,
                              hipStream_t stream) {
    const float* x1 = (const float*)d_in[0];
    const float* x2 = (const float*)d_in[1];
    const float* cg = (const float*)d_in[2];
    float* out = (float*)d_out;
    short* cgT = (short*)d_ws;   // 64*256*2 = 32 KB scratch

    const int B = in_sizes[0] / (TP_L * TP_F);

    prep_cg_kernel<<<TP_NPAD, 256, 0, stream>>>(cg, cgT);
    tp_kernel<<<B, 512, 0, stream>>>(x1, x2, cgT, out);
}